// Round 7
// baseline (457.818 us; speedup 1.0000x reference)
//
#include <hip/hip_runtime.h>

#define N_NODES 50000
#define N_EDGES 800000
#define D 64          // NODE_DIM == MSG_DIM
#define EDIM 4
#define IN_DIM 132    // 2*D + EDIM
#define H3 192        // 3*D
#define XS 65         // XT row stride (floats): 65%32==1 -> transposed writes 2-way/free

// ---------------- CSR build ----------------

__global__ void k_count(const int* __restrict__ dst, int* __restrict__ deg) {
    int e = blockIdx.x * blockDim.x + threadIdx.x;
    if (e < N_EDGES) atomicAdd(&deg[dst[e]], 1);
}

__global__ __launch_bounds__(256) void k_scan1(const int* __restrict__ deg,
                                               int* __restrict__ offsets,
                                               int* __restrict__ bsum) {
    __shared__ int sm[256];
    int tid = threadIdx.x;
    int i = blockIdx.x * 256 + tid;
    int x = (i < N_NODES) ? deg[i] : 0;
    sm[tid] = x;
    __syncthreads();
    for (int s = 1; s < 256; s <<= 1) {
        int v = (tid >= s) ? sm[tid - s] : 0;
        __syncthreads();
        sm[tid] += v;
        __syncthreads();
    }
    if (i < N_NODES) offsets[i] = sm[tid] - x;  // block-local exclusive
    if (tid == 255) bsum[blockIdx.x] = sm[255];
}

__global__ __launch_bounds__(256) void k_scan2(const int* __restrict__ bsum,
                                               int* __restrict__ boff, int nblk) {
    __shared__ int sm[256];
    int tid = threadIdx.x;
    int x = (tid < nblk) ? bsum[tid] : 0;
    sm[tid] = x;
    __syncthreads();
    for (int s = 1; s < 256; s <<= 1) {
        int v = (tid >= s) ? sm[tid - s] : 0;
        __syncthreads();
        sm[tid] += v;
        __syncthreads();
    }
    if (tid < nblk) boff[tid] = sm[tid] - x;  // exclusive
}

__global__ __launch_bounds__(256) void k_scan3(int* __restrict__ offsets,
                                               const int* __restrict__ boff) {
    int i = blockIdx.x * 256 + threadIdx.x;
    if (i < N_NODES) offsets[i] += boff[blockIdx.x];
}

__global__ void k_fill(const int* __restrict__ src, const int* __restrict__ dst,
                       const int* __restrict__ offsets, int* __restrict__ cursor,
                       int* __restrict__ csr_src, int* __restrict__ csr_eid) {
    int e = blockIdx.x * blockDim.x + threadIdx.x;
    if (e < N_EDGES) {
        int d = dst[e];
        int pos = offsets[d] + atomicAdd(&cursor[d], 1);
        csr_src[pos] = src[e];
        csr_eid[pos] = e;
    }
}

// ---------------- fused per-round kernel: gather-sum (phase A) + GEMMs + GRU ----------------
// 512 threads = 8 waves; 64 nodes per block (lane = local node in GEMM phases).
// XT[k][n], k-major, stride XS=65 (all transposed writes/reads land 2-way-or-free on banks).
//   rows 0..63: S^T (gathered) then a^T; rows 64..127: hv^T; 128..131: Hsum^T.
// Phase A: wave w gathers S for its 8 nodes (16-lane x float4, 4 edges in flight, butterfly),
//          writes S^T directly to LDS. Round 0 also computes Hsum (edge-feature sum) and
//          persists it to global for round 1.
// Phase B/C: GEMM1/GEMM2 with wave-uniform weight slices (scalar path), GRU epilogue.

template <int ROUND>
__global__ __launch_bounds__(512) void k_fused(const float* __restrict__ hv_in,
                                               const float* __restrict__ he,
                                               const int* __restrict__ csr_src,
                                               const int* __restrict__ csr_eid,
                                               const int* __restrict__ offsets,
                                               const int* __restrict__ deg,
                                               float* __restrict__ Hsum,
                                               const float* __restrict__ W_msg,
                                               const float* __restrict__ b_msg,
                                               const float* __restrict__ W_ih,
                                               const float* __restrict__ W_hh,
                                               const float* __restrict__ b_ih,
                                               const float* __restrict__ b_hh,
                                               float* __restrict__ hv_out) {
    __shared__ float XT[IN_DIM * XS];  // 34320 B

    const int tid = threadIdx.x;
    const int n_base = blockIdx.x * D;
    const int lane = tid & 63;

    // ---- phase A1: stage hv^T (rows 64..127) + (round1) Hsum^T ----
    {
        int nl = tid >> 3;  // 0..63
        int c8 = tid & 7;   // 8-float chunk
        int n = n_base + nl;
        if (n >= N_NODES) n = N_NODES - 1;
        const float4* Hp = (const float4*)(hv_in + (size_t)n * D);
        float4 h0 = Hp[c8 * 2], h1 = Hp[c8 * 2 + 1];
        int k0 = c8 * 8;
        XT[(64 + k0 + 0) * XS + nl] = h0.x; XT[(64 + k0 + 1) * XS + nl] = h0.y;
        XT[(64 + k0 + 2) * XS + nl] = h0.z; XT[(64 + k0 + 3) * XS + nl] = h0.w;
        XT[(64 + k0 + 4) * XS + nl] = h1.x; XT[(64 + k0 + 5) * XS + nl] = h1.y;
        XT[(64 + k0 + 6) * XS + nl] = h1.z; XT[(64 + k0 + 7) * XS + nl] = h1.w;
        if (ROUND != 0 && c8 == 0) {
            float4 hs = *(const float4*)(Hsum + (size_t)n * EDIM);
            XT[128 * XS + nl] = hs.x; XT[129 * XS + nl] = hs.y;
            XT[130 * XS + nl] = hs.z; XT[131 * XS + nl] = hs.w;
        }
    }

    // ---- phase A2: gather S^T for this block's 64 nodes; wave w owns nodes w*8..w*8+7 ----
    {
        const int w8 = (tid >> 6) * 8;
        const int g = lane >> 4;   // edge slot 0..3
        const int c = lane & 15;   // float4 chunk of the row
        for (int q = 0; q < 8; ++q) {
            const int nl = w8 + q;
            int n = n_base + nl;
            const bool nv = (n < N_NODES);
            if (!nv) n = N_NODES - 1;
            const int off = offsets[n];
            const int cnt = deg[n];
            float4 acc = make_float4(0.f, 0.f, 0.f, 0.f);
            float4 hacc = make_float4(0.f, 0.f, 0.f, 0.f);
            for (int e = g; e < cnt; e += 4) {
                int sn = csr_src[off + e];
                float4 v = ((const float4*)(hv_in + (size_t)sn * D))[c];
                acc.x += v.x; acc.y += v.y; acc.z += v.z; acc.w += v.w;
                if (ROUND == 0 && c == 0) {
                    int eid = csr_eid[off + e];
                    float4 h = *(const float4*)(he + (size_t)eid * EDIM);
                    hacc.x += h.x; hacc.y += h.y; hacc.z += h.z; hacc.w += h.w;
                }
            }
            acc.x += __shfl_xor(acc.x, 16); acc.y += __shfl_xor(acc.y, 16);
            acc.z += __shfl_xor(acc.z, 16); acc.w += __shfl_xor(acc.w, 16);
            acc.x += __shfl_xor(acc.x, 32); acc.y += __shfl_xor(acc.y, 32);
            acc.z += __shfl_xor(acc.z, 32); acc.w += __shfl_xor(acc.w, 32);
            if (g == 0) {  // lanes 0..15: write S^T rows 4c..4c+3 at column nl
                XT[(4 * c + 0) * XS + nl] = acc.x;
                XT[(4 * c + 1) * XS + nl] = acc.y;
                XT[(4 * c + 2) * XS + nl] = acc.z;
                XT[(4 * c + 3) * XS + nl] = acc.w;
            }
            if (ROUND == 0) {
                hacc.x += __shfl_xor(hacc.x, 16); hacc.y += __shfl_xor(hacc.y, 16);
                hacc.z += __shfl_xor(hacc.z, 16); hacc.w += __shfl_xor(hacc.w, 16);
                hacc.x += __shfl_xor(hacc.x, 32); hacc.y += __shfl_xor(hacc.y, 32);
                hacc.z += __shfl_xor(hacc.z, 32); hacc.w += __shfl_xor(hacc.w, 32);
                if (lane == 0) {
                    XT[128 * XS + nl] = hacc.x; XT[129 * XS + nl] = hacc.y;
                    XT[130 * XS + nl] = hacc.z; XT[131 * XS + nl] = hacc.w;
                    if (nv) *(float4*)(Hsum + (size_t)n * EDIM) = hacc;  // for round 1
                }
            }
        }
    }
    __syncthreads();

    // ---- phase B: GEMM1 (acc1 = S@Wa + Hsum@Wc, acc2 = hv@Wb) ----
    const int w = __builtin_amdgcn_readfirstlane(tid) >> 6;  // wave id 0..7 (uniform)
    const int jb = w * 8;
    const int n = n_base + lane;
    const bool nvalid = (n < N_NODES);
    const int nc = nvalid ? n : N_NODES - 1;
    const float degf = (float)deg[nc];

    const float* __restrict__ Wm = W_msg + (size_t)ROUND * IN_DIM * D;

    float acc1[8], acc2[8];
#pragma unroll
    for (int i = 0; i < 8; ++i) { acc1[i] = 0.f; acc2[i] = 0.f; }

#pragma unroll 4
    for (int k = 0; k < 64; ++k) {
        float aS = XT[k * XS + lane];
        float aH = XT[(64 + k) * XS + lane];
        const float* wr1 = Wm + k * D + jb;
        const float* wr2 = Wm + (64 + k) * D + jb;
#pragma unroll
        for (int i = 0; i < 8; ++i) {
            acc1[i] = fmaf(aS, wr1[i], acc1[i]);
            acc2[i] = fmaf(aH, wr2[i], acc2[i]);
        }
    }
#pragma unroll
    for (int q = 0; q < 4; ++q) {
        float aQ = XT[(128 + q) * XS + lane];
        const float* wr = Wm + (128 + q) * D + jb;
#pragma unroll
        for (int i = 0; i < 8; ++i) acc1[i] = fmaf(aQ, wr[i], acc1[i]);
    }

    const float* bmp = b_msg + (size_t)ROUND * D + jb;
    float av[8];
#pragma unroll
    for (int i = 0; i < 8; ++i) av[i] = acc1[i] + degf * (acc2[i] + bmp[i]);

    __syncthreads();  // all waves done reading S rows
#pragma unroll
    for (int i = 0; i < 8; ++i) XT[(jb + i) * XS + lane] = av[i];  // a^T into rows 0..63
    __syncthreads();

    // ---- phase C: GEMM2 + GRU ----
    const float* __restrict__ Wi = W_ih + (size_t)ROUND * D * H3;
    const float* __restrict__ Wh = W_hh + (size_t)ROUND * D * H3;
    const float* bi = b_ih + (size_t)ROUND * H3;
    const float* bh = b_hh + (size_t)ROUND * H3;

    float aR[8], aZ[8], aN[8], aHN[8];
#pragma unroll
    for (int i = 0; i < 8; ++i) {
        aR[i] = bi[jb + i] + bh[jb + i];
        aZ[i] = bi[64 + jb + i] + bh[64 + jb + i];
        aN[i] = bi[128 + jb + i];
        aHN[i] = bh[128 + jb + i];
    }

#pragma unroll 4
    for (int k = 0; k < 64; ++k) {  // A = a^T rows, B = Wi
        float Aa = XT[k * XS + lane];
        const float* wr = Wi + k * H3;
#pragma unroll
        for (int i = 0; i < 8; ++i) {
            aR[i] = fmaf(Aa, wr[jb + i], aR[i]);
            aZ[i] = fmaf(Aa, wr[64 + jb + i], aZ[i]);
            aN[i] = fmaf(Aa, wr[128 + jb + i], aN[i]);
        }
    }
#pragma unroll 4
    for (int k = 0; k < 64; ++k) {  // A = hv^T rows, B = Wh
        float Ah = XT[(64 + k) * XS + lane];
        const float* wr = Wh + k * H3;
#pragma unroll
        for (int i = 0; i < 8; ++i) {
            aR[i] = fmaf(Ah, wr[jb + i], aR[i]);
            aZ[i] = fmaf(Ah, wr[64 + jb + i], aZ[i]);
            aHN[i] = fmaf(Ah, wr[128 + jb + i], aHN[i]);
        }
    }

    float o[8];
#pragma unroll
    for (int i = 0; i < 8; ++i) {
        float r = 1.f / (1.f + __expf(-aR[i]));
        float z = 1.f / (1.f + __expf(-aZ[i]));
        float nin = aN[i] + r * aHN[i];
        float nn = 2.f / (1.f + __expf(-2.f * nin)) - 1.f;  // tanh
        float hold = XT[(64 + jb + i) * XS + lane];
        o[i] = (1.f - z) * nn + z * hold;
    }
    if (nvalid) {
        float4* op = (float4*)(hv_out + (size_t)n * D + jb);
        op[0] = make_float4(o[0], o[1], o[2], o[3]);
        op[1] = make_float4(o[4], o[5], o[6], o[7]);
    }
}

// ---------------- launch ----------------

extern "C" void kernel_launch(void* const* d_in, const int* in_sizes, int n_in,
                              void* d_out, int out_size, void* d_ws, size_t ws_size,
                              hipStream_t stream) {
    const float* hv = (const float*)d_in[0];
    const float* he = (const float*)d_in[1];
    const float* W_msg = (const float*)d_in[2];
    const float* b_msg = (const float*)d_in[3];
    const float* W_ih = (const float*)d_in[4];
    const float* W_hh = (const float*)d_in[5];
    const float* b_ih = (const float*)d_in[6];
    const float* b_hh = (const float*)d_in[7];
    const int* src = (const int*)d_in[8];
    const int* dst = (const int*)d_in[9];
    float* out = (float*)d_out;

    char* p = (char*)d_ws;
    int* deg = (int*)p;        p += (size_t)N_NODES * sizeof(int);
    int* cursor = (int*)p;     p += (size_t)N_NODES * sizeof(int);
    int* offsets = (int*)p;    p += (size_t)N_NODES * sizeof(int);
    int* bsum = (int*)p;       p += 256 * sizeof(int);
    int* boff = (int*)p;       p += 256 * sizeof(int);
    int* csr_src = (int*)p;    p += (size_t)N_EDGES * sizeof(int);
    int* csr_eid = (int*)p;    p += (size_t)N_EDGES * sizeof(int);
    float* Hsum = (float*)p;   p += (size_t)N_NODES * EDIM * sizeof(float);
    float* hv_buf = (float*)p; p += (size_t)N_NODES * D * sizeof(float);

    const int NBLK = (N_NODES + 255) / 256;  // 196

    hipMemsetAsync(deg, 0, N_NODES * sizeof(int), stream);
    hipMemsetAsync(cursor, 0, N_NODES * sizeof(int), stream);

    k_count<<<(N_EDGES + 255) / 256, 256, 0, stream>>>(dst, deg);
    k_scan1<<<NBLK, 256, 0, stream>>>(deg, offsets, bsum);
    k_scan2<<<1, 256, 0, stream>>>(bsum, boff, NBLK);
    k_scan3<<<NBLK, 256, 0, stream>>>(offsets, boff);
    k_fill<<<(N_EDGES + 255) / 256, 256, 0, stream>>>(src, dst, offsets, cursor, csr_src, csr_eid);

    const int GBLK = (N_NODES + 63) / 64;  // 64 nodes per block, 512 threads

    // round 0: read input hv, write hv_buf (also computes + persists Hsum)
    k_fused<0><<<GBLK, 512, 0, stream>>>(hv, he, csr_src, csr_eid, offsets, deg, Hsum,
                                         W_msg, b_msg, W_ih, W_hh, b_ih, b_hh, hv_buf);

    // round 1: read hv_buf, write d_out (Hsum staged from global)
    k_fused<1><<<GBLK, 512, 0, stream>>>(hv_buf, he, csr_src, csr_eid, offsets, deg, Hsum,
                                         W_msg, b_msg, W_ih, W_hh, b_ih, b_hh, out);
}

// Round 8
// 428.502 us; speedup vs baseline: 1.0684x; 1.0684x over previous
//
#include <hip/hip_runtime.h>

#define N_NODES 50000
#define N_EDGES 800000
#define D 64          // NODE_DIM == MSG_DIM
#define EDIM 4
#define IN_DIM 132    // 2*D + EDIM
#define H3 192        // 3*D
#define XS 65         // XT row stride (floats): 65%32==1 -> transposed writes 2-way/free

typedef unsigned short ushort;
typedef __attribute__((ext_vector_type(8))) unsigned short ushort8_t;

__device__ __forceinline__ float bf2f(ushort u) {
    union { unsigned int i; float f; } x;
    x.i = ((unsigned int)u) << 16;
    return x.f;
}
__device__ __forceinline__ ushort f2bf(float f) {
    union { float f; unsigned int i; } x;
    x.f = f;
    unsigned int r = x.i + 0x7FFFu + ((x.i >> 16) & 1u);  // round-to-nearest-even
    return (ushort)(r >> 16);
}

// ---------------- CSR build ----------------

__global__ void k_count(const int* __restrict__ dst, int* __restrict__ deg) {
    int e = blockIdx.x * blockDim.x + threadIdx.x;
    if (e < N_EDGES) atomicAdd(&deg[dst[e]], 1);
}

__global__ __launch_bounds__(256) void k_scan1(const int* __restrict__ deg,
                                               int* __restrict__ offsets,
                                               int* __restrict__ bsum) {
    __shared__ int sm[256];
    int tid = threadIdx.x;
    int i = blockIdx.x * 256 + tid;
    int x = (i < N_NODES) ? deg[i] : 0;
    sm[tid] = x;
    __syncthreads();
    for (int s = 1; s < 256; s <<= 1) {
        int v = (tid >= s) ? sm[tid - s] : 0;
        __syncthreads();
        sm[tid] += v;
        __syncthreads();
    }
    if (i < N_NODES) offsets[i] = sm[tid] - x;  // block-local exclusive
    if (tid == 255) bsum[blockIdx.x] = sm[255];
}

__global__ __launch_bounds__(256) void k_scan2(const int* __restrict__ bsum,
                                               int* __restrict__ boff, int nblk) {
    __shared__ int sm[256];
    int tid = threadIdx.x;
    int x = (tid < nblk) ? bsum[tid] : 0;
    sm[tid] = x;
    __syncthreads();
    for (int s = 1; s < 256; s <<= 1) {
        int v = (tid >= s) ? sm[tid - s] : 0;
        __syncthreads();
        sm[tid] += v;
        __syncthreads();
    }
    if (tid < nblk) boff[tid] = sm[tid] - x;  // exclusive
}

__global__ __launch_bounds__(256) void k_scan3(int* __restrict__ offsets,
                                               const int* __restrict__ boff) {
    int i = blockIdx.x * 256 + threadIdx.x;
    if (i < N_NODES) offsets[i] += boff[blockIdx.x];
}

__global__ void k_fill(const int* __restrict__ src, const int* __restrict__ dst,
                       const int* __restrict__ offsets, int* __restrict__ cursor,
                       int* __restrict__ csr_src, int* __restrict__ csr_eid) {
    int e = blockIdx.x * blockDim.x + threadIdx.x;
    if (e < N_EDGES) {
        int d = dst[e];
        int pos = offsets[d] + atomicAdd(&cursor[d], 1);
        csr_src[pos] = src[e];
        csr_eid[pos] = e;
    }
}

// ---------------- hv -> bf16 mirror ----------------
__global__ __launch_bounds__(256) void k_prep(const float* __restrict__ hv,
                                              ushort* __restrict__ hvb) {
    int i = blockIdx.x * blockDim.x + threadIdx.x;  // one thread = 8 elements
    if (i >= (N_NODES * D) / 8) return;
    const float4* p = (const float4*)(hv + (size_t)i * 8);
    float4 a = p[0], b = p[1];
    ushort8_t o;
    o[0] = f2bf(a.x); o[1] = f2bf(a.y); o[2] = f2bf(a.z); o[3] = f2bf(a.w);
    o[4] = f2bf(b.x); o[5] = f2bf(b.y); o[6] = f2bf(b.z); o[7] = f2bf(b.w);
    *(ushort8_t*)(hvb + (size_t)i * 8) = o;
}

// ---------------- fused per-round kernel: bf16 gather-sum + GEMMs + GRU ----------------
// 512 threads = 8 waves; 64 nodes per block (lane = local node in GEMM phases).
// XT[k][n], k-major, stride XS=65.
//   rows 0..63: S^T (gathered, fp32 accum from bf16 hv) then a^T; 64..127: hv^T (fp32);
//   128..131: Hsum^T.
// Phase A2 gather: wave w owns nodes w*8..w*8+7; 8 edge slots x 8 lanes x ushort8 (16B).
// GEMM/GRU paths all fp32 (only the message-gather values are bf16-rounded).

template <int ROUND>
__global__ __launch_bounds__(512) void k_fused(const float* __restrict__ hv_in,
                                               const ushort* __restrict__ hvb_in,
                                               ushort* __restrict__ hvb_out,
                                               const float* __restrict__ he,
                                               const int* __restrict__ csr_src,
                                               const int* __restrict__ csr_eid,
                                               const int* __restrict__ offsets,
                                               const int* __restrict__ deg,
                                               float* __restrict__ Hsum,
                                               const float* __restrict__ W_msg,
                                               const float* __restrict__ b_msg,
                                               const float* __restrict__ W_ih,
                                               const float* __restrict__ W_hh,
                                               const float* __restrict__ b_ih,
                                               const float* __restrict__ b_hh,
                                               float* __restrict__ hv_out) {
    __shared__ float XT[IN_DIM * XS];  // 34320 B

    const int tid = threadIdx.x;
    const int n_base = blockIdx.x * D;
    const int lane = tid & 63;

    // ---- phase A1: stage hv^T (rows 64..127, fp32) + (round1) Hsum^T ----
    {
        int nl = tid >> 3;  // 0..63
        int c8 = tid & 7;   // 8-float chunk
        int n = n_base + nl;
        if (n >= N_NODES) n = N_NODES - 1;
        const float4* Hp = (const float4*)(hv_in + (size_t)n * D);
        float4 h0 = Hp[c8 * 2], h1 = Hp[c8 * 2 + 1];
        int k0 = c8 * 8;
        XT[(64 + k0 + 0) * XS + nl] = h0.x; XT[(64 + k0 + 1) * XS + nl] = h0.y;
        XT[(64 + k0 + 2) * XS + nl] = h0.z; XT[(64 + k0 + 3) * XS + nl] = h0.w;
        XT[(64 + k0 + 4) * XS + nl] = h1.x; XT[(64 + k0 + 5) * XS + nl] = h1.y;
        XT[(64 + k0 + 6) * XS + nl] = h1.z; XT[(64 + k0 + 7) * XS + nl] = h1.w;
        if (ROUND != 0 && c8 == 0) {
            float4 hs = *(const float4*)(Hsum + (size_t)n * EDIM);
            XT[128 * XS + nl] = hs.x; XT[129 * XS + nl] = hs.y;
            XT[130 * XS + nl] = hs.z; XT[131 * XS + nl] = hs.w;
        }
    }

    // ---- phase A2: bf16 gather S^T; wave w owns nodes w*8..w*8+7 ----
    {
        const int w8 = (tid >> 6) * 8;
        const int g = lane >> 3;   // edge slot 0..7
        const int c = lane & 7;    // ushort8 chunk (features c*8..c*8+7)
        for (int q = 0; q < 8; ++q) {
            const int nl = w8 + q;
            int n = n_base + nl;
            const bool nv = (n < N_NODES);
            if (!nv) n = N_NODES - 1;
            const int off = offsets[n];
            const int cnt = deg[n];
            float acc[8];
#pragma unroll
            for (int i = 0; i < 8; ++i) acc[i] = 0.f;
            float4 hacc = make_float4(0.f, 0.f, 0.f, 0.f);
            for (int e = g; e < cnt; e += 8) {
                int sn = csr_src[off + e];
                ushort8_t v = *(const ushort8_t*)(hvb_in + (size_t)sn * D + c * 8);
#pragma unroll
                for (int i = 0; i < 8; ++i) acc[i] += bf2f(v[i]);
                if (ROUND == 0 && c == 0) {
                    int eid = csr_eid[off + e];
                    float4 h = *(const float4*)(he + (size_t)eid * EDIM);
                    hacc.x += h.x; hacc.y += h.y; hacc.z += h.z; hacc.w += h.w;
                }
            }
            // butterfly across the 8 edge slots (xor 8,16,32 keeps c fixed)
#pragma unroll
            for (int m = 8; m <= 32; m <<= 1)
#pragma unroll
                for (int i = 0; i < 8; ++i) acc[i] += __shfl_xor(acc[i], m);
            if (g == 0) {  // lanes 0..7: write S^T rows c*8..c*8+7 at column nl
#pragma unroll
                for (int i = 0; i < 8; ++i) XT[(c * 8 + i) * XS + nl] = acc[i];
            }
            if (ROUND == 0) {
#pragma unroll
                for (int m = 8; m <= 32; m <<= 1) {
                    hacc.x += __shfl_xor(hacc.x, m); hacc.y += __shfl_xor(hacc.y, m);
                    hacc.z += __shfl_xor(hacc.z, m); hacc.w += __shfl_xor(hacc.w, m);
                }
                if (lane == 0) {
                    XT[128 * XS + nl] = hacc.x; XT[129 * XS + nl] = hacc.y;
                    XT[130 * XS + nl] = hacc.z; XT[131 * XS + nl] = hacc.w;
                    if (nv) *(float4*)(Hsum + (size_t)n * EDIM) = hacc;  // for round 1
                }
            }
        }
    }
    __syncthreads();

    // ---- phase B: GEMM1 (acc1 = S@Wa + Hsum@Wc, acc2 = hv@Wb) ----
    const int w = __builtin_amdgcn_readfirstlane(tid) >> 6;  // wave id 0..7 (uniform)
    const int jb = w * 8;
    const int n = n_base + lane;
    const bool nvalid = (n < N_NODES);
    const int nc = nvalid ? n : N_NODES - 1;
    const float degf = (float)deg[nc];

    const float* __restrict__ Wm = W_msg + (size_t)ROUND * IN_DIM * D;

    float acc1[8], acc2[8];
#pragma unroll
    for (int i = 0; i < 8; ++i) { acc1[i] = 0.f; acc2[i] = 0.f; }

#pragma unroll 4
    for (int k = 0; k < 64; ++k) {
        float aS = XT[k * XS + lane];
        float aH = XT[(64 + k) * XS + lane];
        const float* wr1 = Wm + k * D + jb;
        const float* wr2 = Wm + (64 + k) * D + jb;
#pragma unroll
        for (int i = 0; i < 8; ++i) {
            acc1[i] = fmaf(aS, wr1[i], acc1[i]);
            acc2[i] = fmaf(aH, wr2[i], acc2[i]);
        }
    }
#pragma unroll
    for (int q = 0; q < 4; ++q) {
        float aQ = XT[(128 + q) * XS + lane];
        const float* wr = Wm + (128 + q) * D + jb;
#pragma unroll
        for (int i = 0; i < 8; ++i) acc1[i] = fmaf(aQ, wr[i], acc1[i]);
    }

    const float* bmp = b_msg + (size_t)ROUND * D + jb;
    float av[8];
#pragma unroll
    for (int i = 0; i < 8; ++i) av[i] = acc1[i] + degf * (acc2[i] + bmp[i]);

    __syncthreads();  // all waves done reading S rows
#pragma unroll
    for (int i = 0; i < 8; ++i) XT[(jb + i) * XS + lane] = av[i];  // a^T into rows 0..63
    __syncthreads();

    // ---- phase C: GEMM2 + GRU ----
    const float* __restrict__ Wi = W_ih + (size_t)ROUND * D * H3;
    const float* __restrict__ Wh = W_hh + (size_t)ROUND * D * H3;
    const float* bi = b_ih + (size_t)ROUND * H3;
    const float* bh = b_hh + (size_t)ROUND * H3;

    float aR[8], aZ[8], aN[8], aHN[8];
#pragma unroll
    for (int i = 0; i < 8; ++i) {
        aR[i] = bi[jb + i] + bh[jb + i];
        aZ[i] = bi[64 + jb + i] + bh[64 + jb + i];
        aN[i] = bi[128 + jb + i];
        aHN[i] = bh[128 + jb + i];
    }

#pragma unroll 4
    for (int k = 0; k < 64; ++k) {  // A = a^T rows, B = Wi
        float Aa = XT[k * XS + lane];
        const float* wr = Wi + k * H3;
#pragma unroll
        for (int i = 0; i < 8; ++i) {
            aR[i] = fmaf(Aa, wr[jb + i], aR[i]);
            aZ[i] = fmaf(Aa, wr[64 + jb + i], aZ[i]);
            aN[i] = fmaf(Aa, wr[128 + jb + i], aN[i]);
        }
    }
#pragma unroll 4
    for (int k = 0; k < 64; ++k) {  // A = hv^T rows, B = Wh
        float Ah = XT[(64 + k) * XS + lane];
        const float* wr = Wh + k * H3;
#pragma unroll
        for (int i = 0; i < 8; ++i) {
            aR[i] = fmaf(Ah, wr[jb + i], aR[i]);
            aZ[i] = fmaf(Ah, wr[64 + jb + i], aZ[i]);
            aHN[i] = fmaf(Ah, wr[128 + jb + i], aHN[i]);
        }
    }

    float o[8];
#pragma unroll
    for (int i = 0; i < 8; ++i) {
        float r = 1.f / (1.f + __expf(-aR[i]));
        float z = 1.f / (1.f + __expf(-aZ[i]));
        float nin = aN[i] + r * aHN[i];
        float nn = 2.f / (1.f + __expf(-2.f * nin)) - 1.f;  // tanh
        float hold = XT[(64 + jb + i) * XS + lane];
        o[i] = (1.f - z) * nn + z * hold;
    }
    if (nvalid) {
        float4* op = (float4*)(hv_out + (size_t)n * D + jb);
        op[0] = make_float4(o[0], o[1], o[2], o[3]);
        op[1] = make_float4(o[4], o[5], o[6], o[7]);
        if (ROUND == 0) {  // bf16 mirror for round-1 gather
            ushort8_t ob;
#pragma unroll
            for (int i = 0; i < 8; ++i) ob[i] = f2bf(o[i]);
            *(ushort8_t*)(hvb_out + (size_t)n * D + jb) = ob;
        }
    }
}

// ---------------- launch ----------------

extern "C" void kernel_launch(void* const* d_in, const int* in_sizes, int n_in,
                              void* d_out, int out_size, void* d_ws, size_t ws_size,
                              hipStream_t stream) {
    const float* hv = (const float*)d_in[0];
    const float* he = (const float*)d_in[1];
    const float* W_msg = (const float*)d_in[2];
    const float* b_msg = (const float*)d_in[3];
    const float* W_ih = (const float*)d_in[4];
    const float* W_hh = (const float*)d_in[5];
    const float* b_ih = (const float*)d_in[6];
    const float* b_hh = (const float*)d_in[7];
    const int* src = (const int*)d_in[8];
    const int* dst = (const int*)d_in[9];
    float* out = (float*)d_out;

    char* p = (char*)d_ws;
    int* deg = (int*)p;        p += (size_t)N_NODES * sizeof(int);
    int* cursor = (int*)p;     p += (size_t)N_NODES * sizeof(int);
    int* offsets = (int*)p;    p += (size_t)N_NODES * sizeof(int);
    int* bsum = (int*)p;       p += 256 * sizeof(int);
    int* boff = (int*)p;       p += 256 * sizeof(int);
    int* csr_src = (int*)p;    p += (size_t)N_EDGES * sizeof(int);
    int* csr_eid = (int*)p;    p += (size_t)N_EDGES * sizeof(int);
    float* Hsum = (float*)p;   p += (size_t)N_NODES * EDIM * sizeof(float);
    float* hv_buf = (float*)p; p += (size_t)N_NODES * D * sizeof(float);
    ushort* hvb_A = (ushort*)p; p += (size_t)N_NODES * D * sizeof(ushort);
    ushort* hvb_B = (ushort*)p; p += (size_t)N_NODES * D * sizeof(ushort);

    const int NBLK = (N_NODES + 255) / 256;  // 196

    hipMemsetAsync(deg, 0, N_NODES * sizeof(int), stream);
    hipMemsetAsync(cursor, 0, N_NODES * sizeof(int), stream);

    k_count<<<(N_EDGES + 255) / 256, 256, 0, stream>>>(dst, deg);
    k_scan1<<<NBLK, 256, 0, stream>>>(deg, offsets, bsum);
    k_scan2<<<1, 256, 0, stream>>>(bsum, boff, NBLK);
    k_scan3<<<NBLK, 256, 0, stream>>>(offsets, boff);
    k_fill<<<(N_EDGES + 255) / 256, 256, 0, stream>>>(src, dst, offsets, cursor, csr_src, csr_eid);
    k_prep<<<(N_NODES * D / 8 + 255) / 256, 256, 0, stream>>>(hv, hvb_A);

    const int GBLK = (N_NODES + 63) / 64;  // 64 nodes per block, 512 threads

    // round 0: gather from hvb_A, write hv_buf (fp32) + hvb_B (bf16 mirror) + Hsum
    k_fused<0><<<GBLK, 512, 0, stream>>>(hv, hvb_A, hvb_B, he, csr_src, csr_eid, offsets,
                                         deg, Hsum, W_msg, b_msg, W_ih, W_hh, b_ih, b_hh,
                                         hv_buf);

    // round 1: gather from hvb_B, write d_out
    k_fused<1><<<GBLK, 512, 0, stream>>>(hv_buf, hvb_B, (ushort*)nullptr, he, csr_src,
                                         csr_eid, offsets, deg, Hsum, W_msg, b_msg, W_ih,
                                         W_hh, b_ih, b_hh, out);
}